// Round 6
// baseline (96.073 us; speedup 1.0000x reference)
//
#include <hip/hip_runtime.h>
#include <math.h>

#define BB 4
#define NN 4096
#define DD 128
#define HS 8             // n-stream slices per batch
#define NIT 8            // 64-col n-tiles per slice
#define MGROUPS 128      // m-groups (32 rows) per batch

typedef __attribute__((ext_vector_type(8))) short bf16x8;
typedef __attribute__((ext_vector_type(4))) float f32x4;

__device__ __forceinline__ void mfma_16x16x32_bf16(f32x4& d, bf16x8 a, bf16x8 b) {
  asm volatile("v_mfma_f32_16x16x32_bf16 %0, %1, %2, %0" : "+v"(d) : "v"(a), "v"(b));
}

__device__ __forceinline__ unsigned short f2b(float x) {  // RNE f32->bf16
  union { float f; unsigned u; } v; v.f = x;
  unsigned r = v.u + 0x7fffu + ((v.u >> 16) & 1u);
  return (unsigned short)(r >> 16);
}

// ---- kernel 1: cast to bf16 (ft pre-scaled by 0.1) + fs inv-norms ----------
__global__ __launch_bounds__(256) void k_prep(const float* __restrict__ fs,
                                              const float* __restrict__ ft,
                                              unsigned* __restrict__ outb,
                                              float* __restrict__ inv_norm) {
  int w = threadIdx.x >> 6, lane = threadIdx.x & 63;
  int row = blockIdx.x * 4 + w;
  bool is_s = row < BB * NN;
  const float* src = is_s ? fs + (size_t)row * DD
                          : ft + ((size_t)row - BB * NN) * DD;
  float2 v = ((const float2*)src)[lane];
  float cx = is_s ? v.x : v.x * 0.1f;   // acc becomes dot/temp directly
  float cy = is_s ? v.y : v.y * 0.1f;
  outb[(size_t)row * 64 + lane] = ((unsigned)f2b(cy) << 16) | f2b(cx);
  if (is_s) {
    float s = v.x * v.x + v.y * v.y;
#pragma unroll
    for (int off = 32; off > 0; off >>= 1) s += __shfl_xor(s, off);
    if (lane == 0) inv_norm[row] = 1.0f / sqrtf(s);
  }
}

// ---- kernel 2: barrier-free per-wave GEMM C[m][n] + fused epilogue ---------
// 4096 waves total: wave gw -> b = gw>>10, h = (gw>>7)&7, mg = gw&127.
// Wave owns 32 m-rows (ft, A-frags in regs) and streams 512 n (fs) in 8 tiles
// of 64, fragments loaded straight from global (L1/L2-resident). Per tile:
// exp col-sums -> 2 shfl-adds -> psum partial; argmax over n runs entirely
// in-register via packed keys (value | inverse (it,fj) code in 5 low bits).
// No LDS, no __syncthreads.
__global__ __launch_bounds__(256, 4) void k_main(const unsigned short* __restrict__ fsb,
                                                 const unsigned short* __restrict__ ftb,
                                                 const float* __restrict__ inv_norm,
                                                 float* __restrict__ psum,
                                                 float2* __restrict__ pmax) {
  const int t = threadIdx.x;
  const int w = t >> 6, lane = t & 63;
  const int l15 = lane & 15, g = lane >> 4;
  const int gw = blockIdx.x * 4 + w;     // global wave id, 0..4095
  const int b = gw >> 10;
  const int h = (gw >> 7) & 7;           // n-slice
  const int mg = gw & 127;               // m-group
  const int m0 = mg * 32;

  // A fragments (ft rows m0..m0+31, pre-scaled by 0.1), loaded once: 32 VGPR
  const unsigned short* Abase = ftb + ((size_t)b * NN + m0) * DD;
  bf16x8 af[4][2];
#pragma unroll
  for (int kk = 0; kk < 4; kk++)
#pragma unroll
    for (int mf = 0; mf < 2; mf++)
      af[kk][mf] = *(const bf16x8*)(Abase + (mf * 16 + l15) * DD + kk * 32 + g * 8);

  const unsigned short* Ball = fsb + (size_t)b * NN * DD;
  const float* invb = inv_norm + (size_t)b * NN;

  float bkey[2][4];                      // running packed argmax keys (real keys ~4.0)
#pragma unroll
  for (int mf = 0; mf < 2; mf++)
#pragma unroll
    for (int j = 0; j < 4; j++) bkey[mf][j] = 0.0f;

#pragma unroll 1
  for (int it = 0; it < NIT; ++it) {
    const int n0 = h * 512 + it * 64;
    float svn[4];
#pragma unroll
    for (int fj = 0; fj < 4; fj++) svn[fj] = invb[n0 + fj * 16 + l15];

    f32x4 acc[2][4] = {};
#pragma unroll
    for (int kk = 0; kk < 4; kk++) {
      bf16x8 bf[4];
#pragma unroll
      for (int fj = 0; fj < 4; fj++)
        bf[fj] = *(const bf16x8*)(Ball + (size_t)(n0 + fj * 16 + l15) * DD + kk * 32 + g * 8);
#pragma unroll
      for (int mf = 0; mf < 2; mf++)
#pragma unroll
        for (int fj = 0; fj < 4; fj++)
          mfma_16x16x32_bf16(acc[mf][fj], af[kk][mf], bf[fj]);
    }

    // exp column-sums over this wave's 32 m-rows (acc == dot/temp)
#pragma unroll
    for (int fj = 0; fj < 4; fj++) {
      float s = (__expf(acc[0][fj][0]) + __expf(acc[0][fj][1])) +
                (__expf(acc[0][fj][2]) + __expf(acc[0][fj][3])) +
                (__expf(acc[1][fj][0]) + __expf(acc[1][fj][1])) +
                (__expf(acc[1][fj][2]) + __expf(acc[1][fj][3]));
      s += __shfl_xor(s, 16);
      s += __shfl_xor(s, 32);
      if (g == 0)
        psum[((size_t)b * NN + n0 + fj * 16 + l15) * MGROUPS + mg] = s;
    }

    // packed-key running argmax over n: key = quantized(acc*inv_s + 4) | inv-code
    const unsigned codebase = (unsigned)((7 - it) << 2);
#pragma unroll
    for (int fj = 0; fj < 4; fj++) {
      const unsigned code = codebase | (unsigned)(3 - fj);   // bigger = earlier n
#pragma unroll
      for (int mf = 0; mf < 2; mf++)
#pragma unroll
        for (int j = 0; j < 4; j++) {
          float v = fmaf(acc[mf][fj][j], svn[fj], 4.0f);     // positive -> uint-order
          unsigned kb = (__float_as_uint(v) & 0xFFFFFFE0u) | code;
          bkey[mf][j] = fmaxf(bkey[mf][j], __uint_as_float(kb));
        }
    }
  }

  // finalize: exact cross-lane argmax over the 16 l15 lanes, once
#pragma unroll
  for (int mf = 0; mf < 2; mf++)
#pragma unroll
    for (int j = 0; j < 4; j++) {
      unsigned bits = __float_as_uint(bkey[mf][j]);
      unsigned code = bits & 31u;
      int itw = 7 - (int)(code >> 2);
      int fjw = 3 - (int)(code & 3u);
      int n = h * 512 + itw * 64 + fjw * 16 + l15;
      float vq = __uint_as_float(bits & 0xFFFFFFE0u);
#pragma unroll
      for (int off = 1; off <= 8; off <<= 1) {
        float ov = __shfl_xor(vq, off);
        int   on = __shfl_xor(n, off);
        if (ov > vq || (ov == vq && on < n)) { vq = ov; n = on; }
      }
      if (l15 == 0) {
        int m = m0 + mf * 16 + g * 4 + j;
        float2 pr; pr.x = vq; pr.y = __int_as_float(n);
        pmax[((size_t)b * NN + m) * HS + h] = pr;
      }
    }
}

// ---- kernel 3: per-row finish: argmax over 8 slices, sum 128 psum, pos dot -
__global__ __launch_bounds__(256) void k_post(const float* __restrict__ fs,
                                              const float* __restrict__ ft,
                                              const float* __restrict__ psum,
                                              const float2* __restrict__ pmax,
                                              float* __restrict__ blockpart) {
  __shared__ float part[4];
  int w = threadIdx.x >> 6, lane = threadIdx.x & 63;
  int row = blockIdx.x * 4 + w;          // flat b*N + p
  int b = row >> 12;
  // argmax over the 8 h-slices
  float v = -INFINITY; int i = 0x7fffffff;
  if (lane < HS) {
    float2 pm = pmax[(size_t)row * HS + lane];
    v = pm.x; i = __float_as_int(pm.y);
  }
#pragma unroll
  for (int off = 1; off <= 4; off <<= 1) {
    float ov = __shfl_xor(v, off);
    int   oi = __shfl_xor(i, off);
    if (ov > v || (ov == v && oi < i)) { v = ov; i = oi; }
  }
  int j = __shfl(i, 0);
  // sum of 128 psum partials
  float2 q = ((const float2*)(psum + (size_t)row * MGROUPS))[lane];
  float tot = q.x + q.y;
#pragma unroll
  for (int off = 32; off > 0; off >>= 1) tot += __shfl_xor(tot, off);
  // fp32 dot of fs[row] with ft[b, j]
  float2 a = ((const float2*)(fs + (size_t)row * DD))[lane];
  float2 c = ((const float2*)(ft + ((size_t)b * NN + j) * DD))[lane];
  float s = a.x * c.x + a.y * c.y;
#pragma unroll
  for (int off = 32; off > 0; off >>= 1) s += __shfl_xor(s, off);
  if (lane == 0) {
    float term = logf(tot) - s * 0.1f;
    part[w] = fminf(term, 92.103403719761827f);   // ratio clip at 1e-40
  }
  __syncthreads();
  if (threadIdx.x == 0)
    blockpart[blockIdx.x] = part[0] + part[1] + part[2] + part[3];
}

// ---- kernel 4: final deterministic reduction ------------------------------
__global__ __launch_bounds__(256) void k_final(const float* __restrict__ blockpart,
                                               float* __restrict__ out) {
  __shared__ float red[256];
  float s = 0.0f;
  for (int i = threadIdx.x; i < (BB * NN) / 4; i += 256) s += blockpart[i];
  red[threadIdx.x] = s;
  __syncthreads();
  for (int st = 128; st > 0; st >>= 1) {
    if (threadIdx.x < st) red[threadIdx.x] += red[threadIdx.x + st];
    __syncthreads();
  }
  if (threadIdx.x == 0) out[0] = red[0] * (1.0f / (BB * NN));
}

extern "C" void kernel_launch(void* const* d_in, const int* in_sizes, int n_in,
                              void* d_out, int out_size, void* d_ws, size_t ws_size,
                              hipStream_t stream) {
  const float* fs = (const float*)d_in[0];
  const float* ft = (const float*)d_in[1];
  float* out = (float*)d_out;

  const size_t NE = (size_t)BB * NN * DD;
  unsigned short* fsb = (unsigned short*)d_ws;                   // 4MB
  unsigned short* ftb = fsb + NE;                                // 4MB
  float*  inv_norm = (float*)(ftb + NE);                         // 64KB
  float*  psum     = inv_norm + (size_t)BB * NN;                 // B*N*128 f32 (8MB)
  float2* pmax     = (float2*)(psum + (size_t)BB * NN * MGROUPS);// B*N*8 f32x2 (1MB)
  float*  blockpart = (float*)(pmax + (size_t)BB * NN * HS);     // B*N/4 f32

  k_prep<<<(2 * BB * NN) / 4, 256, 0, stream>>>(fs, ft, (unsigned*)fsb, inv_norm);
  // total waves = BB * HS * MGROUPS = 4096 -> 1024 blocks of 4 waves
  k_main<<<(BB * HS * MGROUPS) / 4, 256, 0, stream>>>(fsb, ftb, inv_norm, psum, pmax);
  k_post<<<(BB * NN) / 4, 256, 0, stream>>>(fs, ft, psum, pmax, blockpart);
  k_final<<<1, 256, 0, stream>>>(blockpart, out);
}